// Round 9
// baseline (144.983 us; speedup 1.0000x reference)
//
#include <hip/hip_runtime.h>

#define BB 32
#define SS 1024
#define EE 256

typedef float f4 __attribute__((ext_vector_type(4)));
typedef int   i4 __attribute__((ext_vector_type(4)));

// One block (256 thr = 4 waves) per batch row: inclusive cumsum of duration.
__global__ void lr_cumsum_kernel(const int* __restrict__ dur, int* __restrict__ cum) {
    __shared__ int wtot[4];
    const int b = blockIdx.x;
    const int tid = threadIdx.x;
    const int lane = tid & 63;
    const int wave = tid >> 6;

    const i4 d = ((const i4*)(dur + b * SS))[tid];
    const int s0 = d.x;
    const int s1 = s0 + d.y;
    const int s2 = s1 + d.z;
    const int s3 = s2 + d.w;
    int inc = s3;
    for (int dd = 1; dd < 64; dd <<= 1) {
        const int y = __shfl_up(inc, dd, 64);
        if (lane >= dd) inc += y;
    }
    if (lane == 63) wtot[wave] = inc;
    __syncthreads();
    int woff = 0;
#pragma unroll
    for (int w = 0; w < 4; ++w) woff += (w < wave) ? wtot[w] : 0;
    const int toff = woff + inc - s3;
    i4 o; o.x = toff + s0; o.y = toff + s1; o.z = toff + s2; o.w = toff + s3;
    ((i4*)(cum + b * SS))[tid] = o;
}

// Fused scatter + folded tail. Grid is exactly SS/4 x BB (8192 blocks; no
// mostly-idle tail blocks). Wave for input row t:
//  - scatter x[b,t] into out rows [cum[t-1], cum[t])  (regular stores, R8 win)
//  - tail: zero-fill output rows {t, t+1024, t+2048, ...} that are >= mel_len
//    (<=4 wave-uniform candidates; ~0.09 fills per wave on average)
__global__ void lr_fused_kernel(const float* __restrict__ x,
                                const int* __restrict__ cum,
                                float* __restrict__ out,
                                float* __restrict__ mask,
                                int max_mel) {
    const int b = blockIdx.y;
    const int wave = threadIdx.x >> 6;      // 4 waves/block
    const int lane = threadIdx.x & 63;
    const int t = blockIdx.x * 4 + wave;    // t in [0, SS)

    const int* crow = cum + b * SS;
    const int mel_len = crow[SS - 1];
    f4* obase = (f4*)(out + (size_t)b * max_mel * EE);
    float* mrow = mask + (size_t)b * max_mel;

    const int c1 = crow[t];
    const int c0 = (t == 0) ? 0 : crow[t - 1];
    if (c1 > c0) {
        const f4* xrow = (const f4*)(x + ((size_t)b * SS + t) * EE);
        const f4 v = __builtin_nontemporal_load(xrow + lane);
        for (int tt = c0; tt < c1; ++tt)    // <=7 independent 1KB stores
            obase[(size_t)tt * (EE / 4) + lane] = v;
        if (lane < c1 - c0) mrow[c0 + lane] = 0.0f;
    }

    // Folded tail: strided candidates, wave-uniform branches.
    const f4 z = {0.f, 0.f, 0.f, 0.f};
    for (int r = t; r < max_mel; r += SS) {
        if (r >= mel_len) {
            obase[(size_t)r * (EE / 4) + lane] = z;
            if (lane == 0) mrow[r] = 1.0f;
        }
    }
}

extern "C" void kernel_launch(void* const* d_in, const int* in_sizes, int n_in,
                              void* d_out, int out_size, void* d_ws, size_t ws_size,
                              hipStream_t stream) {
    const float* x   = (const float*)d_in[0];
    const int*   dur = (const int*)d_in[1];
    float* out = (float*)d_out;

    const int max_mel = out_size / (BB * (EE + 1));
    float* mask = out + (size_t)BB * max_mel * EE;
    int* cum = (int*)d_ws;                  // 128 KB scratch

    lr_cumsum_kernel<<<BB, 256, 0, stream>>>(dur, cum);

    dim3 grid(SS / 4, BB);                  // 8192 blocks, all do real work
    lr_fused_kernel<<<grid, 256, 0, stream>>>(x, cum, out, mask, max_mel);
}